// Round 13
// baseline (917.562 us; speedup 1.0000x reference)
//
#include <hip/hip_runtime.h>
#include <cstdint>
#include <cstddef>

#define T_DIM 8
#define V_DIM 10000
#define E_DIM 100000
#define M_ALL (T_DIM * V_DIM)

typedef __attribute__((ext_vector_type(8))) short short8;
typedef __attribute__((ext_vector_type(4))) float floatx4;

__device__ __forceinline__ unsigned int f2bf(float f) {
    union { float f; unsigned int u; } v; v.f = f;
    unsigned int u = v.u;
    u = u + 0x7FFFu + ((u >> 16) & 1u);   // RNE
    return u >> 16;
}
__device__ __forceinline__ float bf2f(unsigned int s) {
    union { unsigned int u; float f; } v; v.u = s << 16;
    return v.f;
}
__device__ __forceinline__ short8 relu8(short8 x) {
    const short8 z = {0,0,0,0,0,0,0,0};
    return __builtin_elementwise_max(x, z);   // v_pk_max_i16: bf16 relu on bit pattern
}
// HW packed f32->bf16 RNE (no builtin on gfx950)
__device__ __forceinline__ unsigned int cvtpk_bf16(float lo, float hi) {
    unsigned int r;
    asm("v_cvt_pk_bf16_f32 %0, %1, %2" : "=v"(r) : "v"(lo), "v"(hi));
    return r;
}
union PK { uint4 u; short8 s; };

// ---- pack fp32 weight [K,Nw] into MFMA B-fragment order inside a concat buffer
// frag index fo = (kt + kt_off) * NTN_tot + nt_off + nt
__global__ void pack_b_kernel(const float* __restrict__ w, unsigned short* __restrict__ out,
                              int K, int Nw, int NTN_tot, int nt_off, int kt_off) {
    int tid = blockIdx.x * blockDim.x + threadIdx.x;
    int total = (K >> 5) * (Nw >> 4) * 64;
    if (tid >= total) return;
    int lane = tid & 63;
    int f = tid >> 6;
    int ntn_w = Nw >> 4;
    int nt = f % ntn_w;
    int kt = f / ntn_w;
    int kbase = kt * 32 + ((lane >> 4) << 3);
    int n = nt * 16 + (lane & 15);
    unsigned int vals[8];
#pragma unroll
    for (int j = 0; j < 8; ++j)
        vals[j] = f2bf(w[(size_t)(kbase + j) * Nw + n]);
    uint4 pk;
    pk.x = vals[0] | (vals[1] << 16);
    pk.y = vals[2] | (vals[3] << 16);
    pk.z = vals[4] | (vals[5] << 16);
    pk.w = vals[6] | (vals[7] << 16);
    size_t fo = (size_t)(kt + kt_off) * NTN_tot + nt_off + nt;
    *(uint4*)(out + (fo * 64 + lane) * 8) = pk;
}

// ---- token mixer ----
__global__ void token_mix_kernel(const float* __restrict__ xs, const float* __restrict__ w_pre,
                                 const float* __restrict__ b_pre, unsigned short* __restrict__ ob) {
    const int S = V_DIM * 128;
    int tid = blockIdx.x * blockDim.x + threadIdx.x;
    if (tid >= T_DIM * S / 4) return;
    int e = tid * 4;
    int t = e / S;
    int c = e & 127;
    floatx4 xm = {0.f,0.f,0.f,0.f}, xp = {0.f,0.f,0.f,0.f};
    floatx4 x0 = *(const floatx4*)(xs + e);
    if (t > 0)          xm = *(const floatx4*)(xs + e - S);
    if (t < T_DIM - 1)  xp = *(const floatx4*)(xs + e + S);
    uint2 p; unsigned int b[4];
#pragma unroll
    for (int j = 0; j < 4; ++j) {
        int cc = c + j;
        float r = xm[j]*w_pre[cc*3+0] + x0[j]*w_pre[cc*3+1] + xp[j]*w_pre[cc*3+2] + b_pre[cc];
        b[j] = f2bf(r);
    }
    p.x = b[0] | (b[1] << 16);
    p.y = b[2] | (b[3] << 16);
    *(uint2*)(ob + e) = p;
}

// ---- lam[k] = exp(-exp(a[k])) both layers + bmt = b_mix + b_res ----
__global__ void lamb_kernel(const float* __restrict__ a0, const float* __restrict__ a1,
                            const float* __restrict__ bm0, const float* __restrict__ br0,
                            const float* __restrict__ bm1, const float* __restrict__ br1,
                            float* __restrict__ lam0, float* __restrict__ lam1,
                            float* __restrict__ bmt0, float* __restrict__ bmt1) {
    int i = blockIdx.x * blockDim.x + threadIdx.x;
    if (i < 4096) {
        lam0[i] = expf(-expf(a0[i]));
        lam1[i] = expf(-expf(a1[i]));
    }
    if (i < 256) {
        bmt0[i] = bm0[i] + br0[i];
        bmt1[i] = bm1[i] + br1[i];
    }
}

// ================= CSR build =================
__global__ void deg_kernel(const int* __restrict__ ei, int* __restrict__ deg_cnt) {
    int tid = blockIdx.x * blockDim.x + threadIdx.x;
    if (tid >= T_DIM * E_DIM) return;
    int t = tid / E_DIM;
    int e = tid - t * E_DIM;
    int dst = ei[(size_t)t * 2 * E_DIM + E_DIM + e];
    if ((unsigned)dst < V_DIM) atomicAdd(deg_cnt + t * V_DIM + dst, 1);
}

__global__ void invdeg_kernel(const int* __restrict__ deg_cnt, float* __restrict__ inv) {
    int tid = blockIdx.x * blockDim.x + threadIdx.x;
    if (tid >= T_DIM * V_DIM) return;
    inv[tid] = 1.0f / (float)max(deg_cnt[tid], 1);
}

__global__ __launch_bounds__(1024)
void scan_kernel(const int* __restrict__ deg_cnt, int* __restrict__ rowptr) {
    __shared__ int sums[1024];
    int t = blockIdx.x;
    const int* d = deg_cnt + t * V_DIM;
    int* rp = rowptr + t * (V_DIM + 1);
    int tid = threadIdx.x;
    int base = tid * 10;
    int loc[10]; int s = 0;
#pragma unroll
    for (int j = 0; j < 10; ++j) {
        int v = base + j;
        int x = (v < V_DIM) ? d[v] : 0;
        loc[j] = s; s += x;
    }
    sums[tid] = s;
    __syncthreads();
    for (int o = 1; o < 1024; o <<= 1) {
        int v = (tid >= o) ? sums[tid - o] : 0;
        __syncthreads();
        sums[tid] += v;
        __syncthreads();
    }
    int prev = (tid == 0) ? 0 : sums[tid - 1];
#pragma unroll
    for (int j = 0; j < 10; ++j) {
        int v = base + j;
        if (v < V_DIM) rp[v] = prev + loc[j];
    }
    if (tid == 1023) rp[V_DIM] = sums[1023];
}

__global__ void fill_kernel(const int* __restrict__ ei, const int* __restrict__ rowptr,
                            int* __restrict__ fill_cnt, int* __restrict__ srcs) {
    int tid = blockIdx.x * blockDim.x + threadIdx.x;
    if (tid >= T_DIM * E_DIM) return;
    int t = tid / E_DIM;
    int e = tid - t * E_DIM;
    const int* eit = ei + (size_t)t * 2 * E_DIM;
    int src = eit[e];
    int dst = eit[E_DIM + e];
    if ((unsigned)src >= V_DIM || (unsigned)dst >= V_DIM) return;
    int pos = rowptr[t * (V_DIM + 1) + dst] + atomicAdd(fill_cnt + t * V_DIM + dst, 1);
    srcs[(size_t)t * E_DIM + pos] = src;
}

// ---- aggregate raw x (layer 0, 128 ch): xm[t,v] = (sum x[t,src]) * invdeg.
// 256 B rows -> per-t slice 2.56 MB fits XCD L2; XCD-bijective swizzle: XCD j -> t=j.
__global__ void gather_x128_kernel(const unsigned short* __restrict__ x, const int* __restrict__ srcs,
                                   const int* __restrict__ rowptr, const float* __restrict__ invdeg,
                                   unsigned short* __restrict__ xm) {
    int cpx = gridDim.x >> 3;
    int swz = (blockIdx.x & 7) * cpx + (blockIdx.x >> 3);
    int gw = (swz * blockDim.x + threadIdx.x) >> 6;
    int lane = threadIdx.x & 63;
    if (gw >= T_DIM * V_DIM) return;
    int t = gw / V_DIM;
    int v = gw - t * V_DIM;
    const int* rp = rowptr + t * (V_DIM + 1);
    int beg = rp[v], end = rp[v + 1];
    const int* st = srcs + (size_t)t * E_DIM;
    const unsigned short* xt = x + (size_t)t * V_DIM * 128;
    float inv = invdeg[t * V_DIM + v];
    float a0 = 0.f, a1 = 0.f;
    for (int i = beg; i < end; ++i) {
        int s = st[i];
        unsigned int p = *(const unsigned int*)(xt + (size_t)s * 128 + lane * 2);
        a0 += bf2f(p & 0xffffu);
        a1 += bf2f(p >> 16);
    }
    *(unsigned int*)(xm + (size_t)gw * 128 + lane * 2) = cvtpk_bf16(a0 * inv, a1 * inv);
}

// ---- aggregate raw x (layer 1, 256 ch), ONE channel half per LAUNCH.
// Two sequential launches (half=0,1): temporal separation makes the per-XCD
// working set a true 10000 x 256 B = 2.56 MB < 4 MB L2. (Round-12's fused
// 2-half grid interleaved both halves in time -> 5.1 MB thrash, regressed.)
__global__ void gather_x256_half_kernel(const unsigned short* __restrict__ x, const int* __restrict__ srcs,
                                        const int* __restrict__ rowptr, const float* __restrict__ invdeg,
                                        unsigned short* __restrict__ xm, int half) {
    int cpx = gridDim.x >> 3;
    int swz = (blockIdx.x & 7) * cpx + (blockIdx.x >> 3);
    int gw = (swz * blockDim.x + threadIdx.x) >> 6;
    int lane = threadIdx.x & 63;
    if (gw >= T_DIM * V_DIM) return;
    int t = gw / V_DIM;
    int v = gw - t * V_DIM;
    const int* rp = rowptr + t * (V_DIM + 1);
    int beg = rp[v], end = rp[v + 1];
    const int* st = srcs + (size_t)t * E_DIM;
    const unsigned short* xt = x + (size_t)t * V_DIM * 256 + half * 128 + lane * 2;
    float a0 = 0.f, a1 = 0.f;
    for (int i = beg; i < end; ++i) {
        int s = st[i];
        unsigned int p = *(const unsigned int*)(xt + (size_t)s * 256);
        a0 += bf2f(p & 0xffffu);
        a1 += bf2f(p >> 16);
    }
    float inv = invdeg[t * V_DIM + v];
    *(unsigned int*)(xm + (size_t)gw * 256 + half * 128 + lane * 2) =
        cvtpk_bf16(a0 * inv, a1 * inv);
}

// ---- fused SAGE GEMM over all t: h = x@w_self + xm@w_neigh + b_sage, written
// slot-packed to hpack[v][col][t]. Virtual K' = 2*KT*32 (A switches source).
template<int KT>
__global__ __launch_bounds__(256, 4)
void gemm_catf_kernel(const unsigned short* __restrict__ Ax, const unsigned short* __restrict__ Am,
                      const unsigned short* __restrict__ Bp, const float* __restrict__ bias,
                      unsigned short* __restrict__ hpack, int M) {
    const int w = threadIdx.x >> 6, lane = threadIdx.x & 63;
    const int quad = lane >> 4, l16 = lane & 15;
    const int m0 = blockIdx.x * 64;
    constexpr int K = KT * 32;
    floatx4 acc[4][4];
#pragma unroll
    for (int a = 0; a < 4; ++a)
#pragma unroll
        for (int b = 0; b < 4; ++b) acc[a][b] = (floatx4){0.f,0.f,0.f,0.f};
    const unsigned short* arowx[4];
    const unsigned short* arowm[4];
#pragma unroll
    for (int mi = 0; mi < 4; ++mi) {
        int r = m0 + mi * 16 + l16;
        if (r > M - 1) r = M - 1;
        arowx[mi] = Ax + (size_t)r * K + quad * 8;
        arowm[mi] = Am + (size_t)r * K + quad * 8;
    }
    const unsigned short* bptr = Bp + ((size_t)(w * 4) * 64 + lane) * 8;
#pragma unroll
    for (int kt = 0; kt < 2 * KT; ++kt) {
        short8 bfr[4];
#pragma unroll
        for (int i = 0; i < 4; ++i) bfr[i] = *(const short8*)(bptr + i * 512);
        short8 af[4];
#pragma unroll
        for (int mi = 0; mi < 4; ++mi)
            af[mi] = (kt < KT) ? *(const short8*)(arowx[mi] + kt * 32)
                               : *(const short8*)(arowm[mi] + (kt - KT) * 32);
#pragma unroll
        for (int mi = 0; mi < 4; ++mi)
#pragma unroll
            for (int i = 0; i < 4; ++i)
                acc[mi][i] = __builtin_amdgcn_mfma_f32_16x16x32_bf16(af[mi], bfr[i], acc[mi][i], 0, 0, 0);
        bptr += 16 * 512;
    }
    // epilogue: h -> bf16, slot-packed hpack[v*2048 + col*8 + t]
#pragma unroll
    for (int mi = 0; mi < 4; ++mi) {
        int rbase = m0 + mi * 16 + quad * 4;
#pragma unroll
        for (int i = 0; i < 4; ++i) {
            int col = w * 64 + i * 16 + l16;
            float b = bias[col];
#pragma unroll
            for (int rr = 0; rr < 4; ++rr) {
                int row = rbase + rr;
                if (row < M) {
                    int t = row / V_DIM;
                    int v = row - t * V_DIM;
                    hpack[(size_t)v * 2048 + col * 8 + t] = (unsigned short)f2bf(acc[mi][i][rr] + b);
                }
            }
        }
    }
}

// ---- recurrence SSM + mix GEMM + residual, t-chunked + double-buffered Afrag ----
// Block: 16 v-rows x 256 cols x NTC t-outputs; blockIdx.x = t-chunk (T0 runtime).
// Recurrence steps beyond tEnd = T0+NTC are dead for this chunk and skipped
// via wave-uniform guard (chunk 0 runs 4 of 8 steps; static h8.s[t] indexing).
// launch_bounds(256,3): VGPR cap ~170, demand ~110 -> NO SPILL.
// (256,5)/(256,6) spilled catastrophically (r8, r11). (256,3) = 225-228 us.
template<int NTC, int KRT>
__global__ __launch_bounds__(256, 3)
void gemm_mix_rec4_kernel(const unsigned short* __restrict__ hp,   // hpack [V][256][8]
                          const unsigned short* __restrict__ Bp,   // packed [w_mix ; w_res]
                          const unsigned short* __restrict__ Ares, // residual rows [T][V][KR]
                          const float* __restrict__ lam,           // [4096]
                          const float* __restrict__ Bv,            // [4096]
                          const float* __restrict__ bias,          // [256] = b_mix + b_res
                          unsigned short* __restrict__ out,        // rows at (t-OB)*V
                          int T0base, int OB) {
    constexpr int KR = KRT * 32;
    __shared__ __align__(16) unsigned short Afrag[2][4 * NTC * 64 * 8];
    const int tid = threadIdx.x;
    const int w = tid >> 6, lane = tid & 63;
    const int quad = lane >> 4, l16 = lane & 15;
    const int T0 = T0base + blockIdx.x * NTC;
    const int tEnd = T0 + NTC;
    const int m0 = blockIdx.y * 16;
    // phase-1 assignment: 16 rows x 16 octets (8 k each) = 128 k per phase
    const int prow = tid & 15;
    const int oct  = tid >> 4;           // 0..15
    const int kt_w = oct >> 2, qo = oct & 3;
    const int vr = m0 + prow;

    floatx4 acc[NTC][4];
#pragma unroll
    for (int t = 0; t < NTC; ++t)
#pragma unroll
        for (int i = 0; i < 4; ++i) acc[t][i] = (floatx4){0.f,0.f,0.f,0.f};

    const unsigned short* bptr = Bp + ((size_t)(w * 4) * 64 + lane) * 8;

    auto compute = [&](int ph, int buf) {
        const int kg = ph * 128 + kt_w * 32 + qo * 8;
        const int ch = kg >> 4;
        PK h8; h8.u = *(const uint4*)(hp + (size_t)vr * 2048 + (size_t)ch * 8);
        floatx4 l0 = *(const floatx4*)(lam + kg);
        floatx4 l1 = *(const floatx4*)(lam + kg + 4);
        floatx4 b0 = *(const floatx4*)(Bv + kg);
        floatx4 b1 = *(const floatx4*)(Bv + kg + 4);
        floatx4 sA = {0.f,0.f,0.f,0.f}, sB = {0.f,0.f,0.f,0.f};
        unsigned short* ap = Afrag[buf] + ((size_t)(kt_w * NTC) * 64 + qo * 16 + prow) * 8;
#pragma unroll
        for (int t = 0; t < 8; ++t) {
            if (t < tEnd) {   // wave-uniform: chunk 0 skips dead t >= NTC
                float hv = bf2f((unsigned int)(unsigned short)h8.s[t]);
                floatx4 hvv = {hv, hv, hv, hv};
                sA = l0 * sA + hvv * b0;     // v_pk_fma_f32
                sB = l1 * sB + hvv * b1;
                if ((unsigned)(t - T0) < (unsigned)NTC) {
                    PK cv;
                    cv.u.x = cvtpk_bf16(sA[0], sA[1]);
                    cv.u.y = cvtpk_bf16(sA[2], sA[3]);
                    cv.u.z = cvtpk_bf16(sB[0], sB[1]);
                    cv.u.w = cvtpk_bf16(sB[2], sB[3]);
                    PK st; st.s = relu8(cv.s);
                    *(uint4*)(ap + (size_t)(t - T0) * 512) = st.u;   // ds_write_b128
                }
            }
        }
    };
    auto consume = [&](int buf) {
#pragma unroll
        for (int kt = 0; kt < 4; ++kt) {
            short8 bfr[4];
#pragma unroll
            for (int i = 0; i < 4; ++i) bfr[i] = *(const short8*)(bptr + i * 512);
            __builtin_amdgcn_s_setprio(1);
#pragma unroll
            for (int ts = 0; ts < NTC; ++ts) {
                short8 af = *(const short8*)(Afrag[buf] + (size_t)((kt * NTC + ts) * 64 + lane) * 8);
#pragma unroll
                for (int i = 0; i < 4; ++i)
                    acc[ts][i] = __builtin_amdgcn_mfma_f32_16x16x32_bf16(af, bfr[i], acc[ts][i], 0, 0, 0);
            }
            __builtin_amdgcn_s_setprio(0);
            bptr += 16 * 512;
        }
    };

    compute(0, 0);
    __syncthreads();
    for (int ph = 0; ph < 32; ++ph) {
        if (ph < 31) compute(ph + 1, (ph + 1) & 1);
        consume(ph & 1);
        __syncthreads();
    }

    // ---- residual tail: acc[ts] += x(T0+ts) @ w_res ----
#pragma unroll
    for (int ktr = 0; ktr < KRT; ++ktr) {
        short8 bfr[4];
#pragma unroll
        for (int i = 0; i < 4; ++i) bfr[i] = *(const short8*)(bptr + i * 512);
#pragma unroll
        for (int ts = 0; ts < NTC; ++ts) {
            const unsigned short* ar = Ares + ((size_t)(T0 + ts) * V_DIM + (size_t)(m0 + l16)) * KR + ktr * 32 + quad * 8;
            short8 af = *(const short8*)ar;
#pragma unroll
            for (int i = 0; i < 4; ++i)
                acc[ts][i] = __builtin_amdgcn_mfma_f32_16x16x32_bf16(af, bfr[i], acc[ts][i], 0, 0, 0);
        }
        bptr += 16 * 512;
    }
    // ---- epilogue: bias + bf16 store, per chunk t ----
#pragma unroll
    for (int ts = 0; ts < NTC; ++ts) {
#pragma unroll
        for (int i = 0; i < 4; ++i) {
            int col = w * 64 + i * 16 + l16;
            float b = bias[col];
#pragma unroll
            for (int rr = 0; rr < 4; ++rr) {
                int row = m0 + quad * 4 + rr;
                out[((size_t)(T0 + ts - OB) * V_DIM + row) * 256 + col] = (unsigned short)f2bf(acc[ts][i][rr] + b);
            }
        }
    }
}

// ---- small GEMM (head): 32-row blocks, 8 waves ----
template<int NT, int NTN_TOT, bool RELU>
__global__ __launch_bounds__(512)
void gemm16_kernel(const unsigned short* __restrict__ A, const unsigned short* __restrict__ Bp,
                   const float* __restrict__ bias, float* __restrict__ outF, int M, int K) {
    const int w = threadIdx.x >> 6, lane = threadIdx.x & 63;
    const int quad = lane >> 4, l16 = lane & 15;
    const int rowgrp = w >> 2, nchunk = w & 3;
    const int m0 = blockIdx.x * 32 + rowgrp * 16;
    const int ntb = nchunk * NT;
    constexpr int Ntot = NTN_TOT * 16;
    floatx4 acc[NT];
#pragma unroll
    for (int i = 0; i < NT; ++i) acc[i] = (floatx4){0.f,0.f,0.f,0.f};
    int r = m0 + l16; if (r > M - 1) r = M - 1;
    const unsigned short* arow = A + (size_t)r * K + quad * 8;
    const int ksteps = K >> 5;
    for (int kt = 0; kt < ksteps; ++kt) {
        short8 af = *(const short8*)(arow + kt * 32);
        if (RELU) af = relu8(af);
#pragma unroll
        for (int i = 0; i < NT; ++i) {
            short8 bf = *(const short8*)(Bp + ((size_t)(kt * NTN_TOT + ntb + i) * 64 + lane) * 8);
            acc[i] = __builtin_amdgcn_mfma_f32_16x16x32_bf16(af, bf, acc[i], 0, 0, 0);
        }
    }
    const int rbase = m0 + quad * 4;
#pragma unroll
    for (int i = 0; i < NT; ++i) {
        int col = (ntb + i) * 16 + l16;
        float b = bias[col];
#pragma unroll
        for (int rr = 0; rr < 4; ++rr) {
            int row = rbase + rr;
            if (row < M)
                outF[(size_t)row * Ntot + col] = acc[i][rr] + b;
        }
    }
}

extern "C" void kernel_launch(void* const* d_in, const int* in_sizes, int n_in,
                              void* d_out, int out_size, void* d_ws, size_t ws_size,
                              hipStream_t stream) {
    const float* xs      = (const float*)d_in[0];
    const int*   ei      = (const int*)d_in[1];
    const float* w_pre   = (const float*)d_in[2];
    const float* b_pre   = (const float*)d_in[3];
    const float* w_res0  = (const float*)d_in[4];
    const float* b_res0  = (const float*)d_in[5];
    const float* w_self0 = (const float*)d_in[6];
    const float* w_neigh0= (const float*)d_in[7];
    const float* b_sage0 = (const float*)d_in[8];
    const float* a_log0  = (const float*)d_in[9];
    const float* B0      = (const float*)d_in[10];
    const float* w_mix0  = (const float*)d_in[11];
    const float* b_mix0  = (const float*)d_in[12];
    const float* w_res1  = (const float*)d_in[13];
    const float* b_res1  = (const float*)d_in[14];
    const float* w_self1 = (const float*)d_in[15];
    const float* w_neigh1= (const float*)d_in[16];
    const float* b_sage1 = (const float*)d_in[17];
    const float* a_log1  = (const float*)d_in[18];
    const float* B1      = (const float*)d_in[19];
    const float* w_mix1  = (const float*)d_in[20];
    const float* b_mix1  = (const float*)d_in[21];
    const float* w_out   = (const float*)d_in[22];
    const float* b_out   = (const float*)d_in[23];

    char* wsB = (char*)d_ws;
    size_t off = 0;
    auto alloc = [&](size_t bytes) {
        char* p = wsB + off;
        off += (bytes + 255) & ~(size_t)255;
        return p;
    };
    unsigned short* x0b   = (unsigned short*)alloc((size_t)M_ALL * 128 * 2);   // token-mixed input, all t
    unsigned short* xm    = (unsigned short*)alloc((size_t)M_ALL * 256 * 2);   // aggregated-x (both layers)
    unsigned short* hpack = (unsigned short*)alloc((size_t)V_DIM * 2048 * 2);  // [V][256][8] (both layers)
    unsigned short* x1b   = (unsigned short*)alloc((size_t)M_ALL * 256 * 2);   // layer-0 output, all t
    unsigned short* out1_b= (unsigned short*)alloc((size_t)V_DIM * 256 * 2);
    int*            deg_cnt = (int*)alloc((size_t)T_DIM * V_DIM * 4);
    float*          invdeg  = (float*)alloc((size_t)T_DIM * V_DIM * 4);
    int*            rowptr  = (int*)alloc((size_t)T_DIM * (V_DIM + 1) * 4);
    int*            fill_cnt= (int*)alloc((size_t)T_DIM * V_DIM * 4);
    int*            srcs    = (int*)alloc((size_t)T_DIM * E_DIM * 4);
    float*          lam0  = (float*)alloc(4096 * 4);
    float*          lam1  = (float*)alloc(4096 * 4);
    float*          bmt0  = (float*)alloc(256 * 4);
    float*          bmt1  = (float*)alloc(256 * 4);
    unsigned short* wcat0p= (unsigned short*)alloc((size_t)256 * 256 * 2);   // [self;neigh] K'=256
    unsigned short* wcat1p= (unsigned short*)alloc((size_t)512 * 256 * 2);   // [self;neigh] K'=512
    unsigned short* wmix0p= (unsigned short*)alloc((size_t)(4096 + 128) * 256 * 2);
    unsigned short* wmix1p= (unsigned short*)alloc((size_t)(4096 + 256) * 256 * 2);
    unsigned short* woutp = (unsigned short*)alloc((size_t)256 * 64 * 2);
    if (off > ws_size) return;   // fail cleanly, not a GPU fault

    auto cdiv = [](int a, int b) { return (a + b - 1) / b; };
    const int gMall = M_ALL / 64;               // 1250 (exact)
    const int gGat  = M_ALL / 4;                // 20000 blocks, 4 rows each (div by 8)

    // ---- parameter prep ----
    lamb_kernel<<<16, 256, 0, stream>>>(a_log0, a_log1, b_mix0, b_res0, b_mix1, b_res1,
                                        lam0, lam1, bmt0, bmt1);
    // fused SAGE weights: [w_self ; w_neigh] along K, NTN_tot = 16
    pack_b_kernel<<<cdiv(4*16*64, 256), 256, 0, stream>>>(w_self0,  wcat0p, 128, 256, 16, 0, 0);
    pack_b_kernel<<<cdiv(4*16*64, 256), 256, 0, stream>>>(w_neigh0, wcat0p, 128, 256, 16, 0, 4);
    pack_b_kernel<<<cdiv(8*16*64, 256), 256, 0, stream>>>(w_self1,  wcat1p, 256, 256, 16, 0, 0);
    pack_b_kernel<<<cdiv(8*16*64, 256), 256, 0, stream>>>(w_neigh1, wcat1p, 256, 256, 16, 0, 8);
    // mix weights with residual appended along K (kt_off = 128)
    pack_b_kernel<<<cdiv(128*16*64, 256), 256, 0, stream>>>(w_mix0, wmix0p, 4096, 256, 16, 0, 0);
    pack_b_kernel<<<cdiv(4*16*64, 256),   256, 0, stream>>>(w_res0, wmix0p, 128,  256, 16, 0, 128);
    pack_b_kernel<<<cdiv(128*16*64, 256), 256, 0, stream>>>(w_mix1, wmix1p, 4096, 256, 16, 0, 0);
    pack_b_kernel<<<cdiv(8*16*64, 256),   256, 0, stream>>>(w_res1, wmix1p, 256,  256, 16, 0, 128);
    pack_b_kernel<<<cdiv(8*4*64, 256), 256, 0, stream>>>(w_out, woutp, 256, 64, 4, 0, 0);

    // ---- token mixer + CSR build ----
    token_mix_kernel<<<cdiv(T_DIM*V_DIM*128/4, 256), 256, 0, stream>>>(xs, w_pre, b_pre, x0b);
    hipMemsetAsync(deg_cnt, 0, (size_t)T_DIM * V_DIM * 4, stream);
    hipMemsetAsync(fill_cnt, 0, (size_t)T_DIM * V_DIM * 4, stream);
    deg_kernel<<<cdiv(T_DIM*E_DIM, 256), 256, 0, stream>>>(ei, deg_cnt);
    scan_kernel<<<T_DIM, 1024, 0, stream>>>(deg_cnt, rowptr);
    invdeg_kernel<<<cdiv(T_DIM*V_DIM, 256), 256, 0, stream>>>(deg_cnt, invdeg);
    fill_kernel<<<cdiv(T_DIM*E_DIM, 256), 256, 0, stream>>>(ei, rowptr, fill_cnt, srcs);

    // ================= layer 0 (batched over all t) =================
    gather_x128_kernel<<<gGat, 256, 0, stream>>>(x0b, srcs, rowptr, invdeg, xm);
    gemm_catf_kernel<4><<<gMall, 256, 0, stream>>>(x0b, xm, wcat0p, b_sage0, hpack, M_ALL);
    gemm_mix_rec4_kernel<4, 4><<<dim3(2, V_DIM / 16), 256, 0, stream>>>(
        hpack, wmix0p, x0b, lam0, B0, bmt0, x1b, 0, 0);

    // ================= layer 1 (batched over all t; mix only at t=7) =================
    gather_x256_half_kernel<<<gGat, 256, 0, stream>>>(x1b, srcs, rowptr, invdeg, xm, 0);
    gather_x256_half_kernel<<<gGat, 256, 0, stream>>>(x1b, srcs, rowptr, invdeg, xm, 1);
    gemm_catf_kernel<8><<<gMall, 256, 0, stream>>>(x1b, xm, wcat1p, b_sage1, hpack, M_ALL);
    gemm_mix_rec4_kernel<1, 8><<<dim3(1, V_DIM / 16), 256, 0, stream>>>(
        hpack, wmix1p, x1b, lam1, B1, bmt1, out1_b, 7, 7);

    // ================= head =================
    gemm16_kernel<1, 4, false><<<cdiv(V_DIM,32), 512, 0, stream>>>(
        out1_b, woutp, b_out, (float*)d_out, V_DIM, 256);
}

// Round 14
// 875.463 us; speedup vs baseline: 1.0481x; 1.0481x over previous
//
#include <hip/hip_runtime.h>
#include <cstdint>
#include <cstddef>

#define T_DIM 8
#define V_DIM 10000
#define E_DIM 100000
#define M_ALL (T_DIM * V_DIM)

typedef __attribute__((ext_vector_type(8))) short short8;
typedef __attribute__((ext_vector_type(4))) float floatx4;

__device__ __forceinline__ unsigned int f2bf(float f) {
    union { float f; unsigned int u; } v; v.f = f;
    unsigned int u = v.u;
    u = u + 0x7FFFu + ((u >> 16) & 1u);   // RNE
    return u >> 16;
}
__device__ __forceinline__ float bf2f(unsigned int s) {
    union { unsigned int u; float f; } v; v.u = s << 16;
    return v.f;
}
__device__ __forceinline__ short8 relu8(short8 x) {
    const short8 z = {0,0,0,0,0,0,0,0};
    return __builtin_elementwise_max(x, z);   // v_pk_max_i16: bf16 relu on bit pattern
}
// HW packed f32->bf16 RNE (no builtin on gfx950)
__device__ __forceinline__ unsigned int cvtpk_bf16(float lo, float hi) {
    unsigned int r;
    asm("v_cvt_pk_bf16_f32 %0, %1, %2" : "=v"(r) : "v"(lo), "v"(hi));
    return r;
}
union PK { uint4 u; short8 s; };

// ---- pack fp32 weight [K,Nw] into MFMA B-fragment order inside a concat buffer
// frag index fo = (kt + kt_off) * NTN_tot + nt_off + nt
__global__ void pack_b_kernel(const float* __restrict__ w, unsigned short* __restrict__ out,
                              int K, int Nw, int NTN_tot, int nt_off, int kt_off) {
    int tid = blockIdx.x * blockDim.x + threadIdx.x;
    int total = (K >> 5) * (Nw >> 4) * 64;
    if (tid >= total) return;
    int lane = tid & 63;
    int f = tid >> 6;
    int ntn_w = Nw >> 4;
    int nt = f % ntn_w;
    int kt = f / ntn_w;
    int kbase = kt * 32 + ((lane >> 4) << 3);
    int n = nt * 16 + (lane & 15);
    unsigned int vals[8];
#pragma unroll
    for (int j = 0; j < 8; ++j)
        vals[j] = f2bf(w[(size_t)(kbase + j) * Nw + n]);
    uint4 pk;
    pk.x = vals[0] | (vals[1] << 16);
    pk.y = vals[2] | (vals[3] << 16);
    pk.z = vals[4] | (vals[5] << 16);
    pk.w = vals[6] | (vals[7] << 16);
    size_t fo = (size_t)(kt + kt_off) * NTN_tot + nt_off + nt;
    *(uint4*)(out + (fo * 64 + lane) * 8) = pk;
}

// ---- token mixer ----
__global__ void token_mix_kernel(const float* __restrict__ xs, const float* __restrict__ w_pre,
                                 const float* __restrict__ b_pre, unsigned short* __restrict__ ob) {
    const int S = V_DIM * 128;
    int tid = blockIdx.x * blockDim.x + threadIdx.x;
    if (tid >= T_DIM * S / 4) return;
    int e = tid * 4;
    int t = e / S;
    int c = e & 127;
    floatx4 xm = {0.f,0.f,0.f,0.f}, xp = {0.f,0.f,0.f,0.f};
    floatx4 x0 = *(const floatx4*)(xs + e);
    if (t > 0)          xm = *(const floatx4*)(xs + e - S);
    if (t < T_DIM - 1)  xp = *(const floatx4*)(xs + e + S);
    uint2 p; unsigned int b[4];
#pragma unroll
    for (int j = 0; j < 4; ++j) {
        int cc = c + j;
        float r = xm[j]*w_pre[cc*3+0] + x0[j]*w_pre[cc*3+1] + xp[j]*w_pre[cc*3+2] + b_pre[cc];
        b[j] = f2bf(r);
    }
    p.x = b[0] | (b[1] << 16);
    p.y = b[2] | (b[3] << 16);
    *(uint2*)(ob + e) = p;
}

// ---- lam[k] = exp(-exp(a[k])) both layers + bmt = b_mix + b_res ----
__global__ void lamb_kernel(const float* __restrict__ a0, const float* __restrict__ a1,
                            const float* __restrict__ bm0, const float* __restrict__ br0,
                            const float* __restrict__ bm1, const float* __restrict__ br1,
                            float* __restrict__ lam0, float* __restrict__ lam1,
                            float* __restrict__ bmt0, float* __restrict__ bmt1) {
    int i = blockIdx.x * blockDim.x + threadIdx.x;
    if (i < 4096) {
        lam0[i] = expf(-expf(a0[i]));
        lam1[i] = expf(-expf(a1[i]));
    }
    if (i < 256) {
        bmt0[i] = bm0[i] + br0[i];
        bmt1[i] = bm1[i] + br1[i];
    }
}

// ================= CSR build =================
__global__ void deg_kernel(const int* __restrict__ ei, int* __restrict__ deg_cnt) {
    int tid = blockIdx.x * blockDim.x + threadIdx.x;
    if (tid >= T_DIM * E_DIM) return;
    int t = tid / E_DIM;
    int e = tid - t * E_DIM;
    int dst = ei[(size_t)t * 2 * E_DIM + E_DIM + e];
    if ((unsigned)dst < V_DIM) atomicAdd(deg_cnt + t * V_DIM + dst, 1);
}

__global__ void invdeg_kernel(const int* __restrict__ deg_cnt, float* __restrict__ inv) {
    int tid = blockIdx.x * blockDim.x + threadIdx.x;
    if (tid >= T_DIM * V_DIM) return;
    inv[tid] = 1.0f / (float)max(deg_cnt[tid], 1);
}

__global__ __launch_bounds__(1024)
void scan_kernel(const int* __restrict__ deg_cnt, int* __restrict__ rowptr) {
    __shared__ int sums[1024];
    int t = blockIdx.x;
    const int* d = deg_cnt + t * V_DIM;
    int* rp = rowptr + t * (V_DIM + 1);
    int tid = threadIdx.x;
    int base = tid * 10;
    int loc[10]; int s = 0;
#pragma unroll
    for (int j = 0; j < 10; ++j) {
        int v = base + j;
        int x = (v < V_DIM) ? d[v] : 0;
        loc[j] = s; s += x;
    }
    sums[tid] = s;
    __syncthreads();
    for (int o = 1; o < 1024; o <<= 1) {
        int v = (tid >= o) ? sums[tid - o] : 0;
        __syncthreads();
        sums[tid] += v;
        __syncthreads();
    }
    int prev = (tid == 0) ? 0 : sums[tid - 1];
#pragma unroll
    for (int j = 0; j < 10; ++j) {
        int v = base + j;
        if (v < V_DIM) rp[v] = prev + loc[j];
    }
    if (tid == 1023) rp[V_DIM] = sums[1023];
}

__global__ void fill_kernel(const int* __restrict__ ei, const int* __restrict__ rowptr,
                            int* __restrict__ fill_cnt, int* __restrict__ srcs) {
    int tid = blockIdx.x * blockDim.x + threadIdx.x;
    if (tid >= T_DIM * E_DIM) return;
    int t = tid / E_DIM;
    int e = tid - t * E_DIM;
    const int* eit = ei + (size_t)t * 2 * E_DIM;
    int src = eit[e];
    int dst = eit[E_DIM + e];
    if ((unsigned)src >= V_DIM || (unsigned)dst >= V_DIM) return;
    int pos = rowptr[t * (V_DIM + 1) + dst] + atomicAdd(fill_cnt + t * V_DIM + dst, 1);
    srcs[(size_t)t * E_DIM + pos] = src;
}

// ---- aggregate raw x: xm[t,v] = (sum_{src} x[t,src]) * invdeg  (linearity:
// mean(x@W) = mean(x)@W). XCD-bijective swizzle so XCD j handles t=j.
// Plain fused gather measured BEST (r10): both half-split variants (concurrent
// r12, sequential r13) regressed — degree-16 reuse is not L2-limited here.
template<int CH>
__global__ void gather_x_kernel(const unsigned short* __restrict__ x, const int* __restrict__ srcs,
                                const int* __restrict__ rowptr, const float* __restrict__ invdeg,
                                unsigned short* __restrict__ xm) {
    int cpx = gridDim.x >> 3;
    int swz = (blockIdx.x & 7) * cpx + (blockIdx.x >> 3);
    int gw = (swz * blockDim.x + threadIdx.x) >> 6;
    int lane = threadIdx.x & 63;
    if (gw >= T_DIM * V_DIM) return;
    int t = gw / V_DIM;
    int v = gw - t * V_DIM;
    const int* rp = rowptr + t * (V_DIM + 1);
    int beg = rp[v], end = rp[v + 1];
    const int* st = srcs + (size_t)t * E_DIM;
    const unsigned short* xt = x + (size_t)t * V_DIM * CH;
    float inv = invdeg[t * V_DIM + v];
    if (CH == 128) {
        float a0 = 0.f, a1 = 0.f;
        for (int i = beg; i < end; ++i) {
            int s = st[i];
            unsigned int p = *(const unsigned int*)(xt + (size_t)s * 128 + lane * 2);
            a0 += bf2f(p & 0xffffu);
            a1 += bf2f(p >> 16);
        }
        *(unsigned int*)(xm + (size_t)gw * 128 + lane * 2) = cvtpk_bf16(a0 * inv, a1 * inv);
    } else {
        float a0 = 0.f, a1 = 0.f, a2 = 0.f, a3 = 0.f;
        for (int i = beg; i < end; ++i) {
            int s = st[i];
            uint2 p = *(const uint2*)(xt + (size_t)s * 256 + lane * 4);
            a0 += bf2f(p.x & 0xffffu);
            a1 += bf2f(p.x >> 16);
            a2 += bf2f(p.y & 0xffffu);
            a3 += bf2f(p.y >> 16);
        }
        uint2 o;
        o.x = cvtpk_bf16(a0 * inv, a1 * inv);
        o.y = cvtpk_bf16(a2 * inv, a3 * inv);
        *(uint2*)(xm + (size_t)gw * 256 + lane * 4) = o;
    }
}

// ---- fused SAGE GEMM over all t: h = x@w_self + xm@w_neigh + b_sage, written
// slot-packed to hpack[v][col][t]. Virtual K' = 2*KT*32 (A switches source).
template<int KT>
__global__ __launch_bounds__(256, 4)
void gemm_catf_kernel(const unsigned short* __restrict__ Ax, const unsigned short* __restrict__ Am,
                      const unsigned short* __restrict__ Bp, const float* __restrict__ bias,
                      unsigned short* __restrict__ hpack, int M) {
    const int w = threadIdx.x >> 6, lane = threadIdx.x & 63;
    const int quad = lane >> 4, l16 = lane & 15;
    const int m0 = blockIdx.x * 64;
    constexpr int K = KT * 32;
    floatx4 acc[4][4];
#pragma unroll
    for (int a = 0; a < 4; ++a)
#pragma unroll
        for (int b = 0; b < 4; ++b) acc[a][b] = (floatx4){0.f,0.f,0.f,0.f};
    const unsigned short* arowx[4];
    const unsigned short* arowm[4];
#pragma unroll
    for (int mi = 0; mi < 4; ++mi) {
        int r = m0 + mi * 16 + l16;
        if (r > M - 1) r = M - 1;
        arowx[mi] = Ax + (size_t)r * K + quad * 8;
        arowm[mi] = Am + (size_t)r * K + quad * 8;
    }
    const unsigned short* bptr = Bp + ((size_t)(w * 4) * 64 + lane) * 8;
#pragma unroll
    for (int kt = 0; kt < 2 * KT; ++kt) {
        short8 bfr[4];
#pragma unroll
        for (int i = 0; i < 4; ++i) bfr[i] = *(const short8*)(bptr + i * 512);
        short8 af[4];
#pragma unroll
        for (int mi = 0; mi < 4; ++mi)
            af[mi] = (kt < KT) ? *(const short8*)(arowx[mi] + kt * 32)
                               : *(const short8*)(arowm[mi] + (kt - KT) * 32);
#pragma unroll
        for (int mi = 0; mi < 4; ++mi)
#pragma unroll
            for (int i = 0; i < 4; ++i)
                acc[mi][i] = __builtin_amdgcn_mfma_f32_16x16x32_bf16(af[mi], bfr[i], acc[mi][i], 0, 0, 0);
        bptr += 16 * 512;
    }
    // epilogue: h -> bf16, slot-packed hpack[v*2048 + col*8 + t]
#pragma unroll
    for (int mi = 0; mi < 4; ++mi) {
        int rbase = m0 + mi * 16 + quad * 4;
#pragma unroll
        for (int i = 0; i < 4; ++i) {
            int col = w * 64 + i * 16 + l16;
            float b = bias[col];
#pragma unroll
            for (int rr = 0; rr < 4; ++rr) {
                int row = rbase + rr;
                if (row < M) {
                    int t = row / V_DIM;
                    int v = row - t * V_DIM;
                    hpack[(size_t)v * 2048 + col * 8 + t] = (unsigned short)f2bf(acc[mi][i][rr] + b);
                }
            }
        }
    }
}

// ---- recurrence SSM + mix GEMM + residual, t-chunked + double-buffered Afrag ----
// Block: 16 v-rows x 256 cols x NTC t-outputs; blockIdx.x = t-chunk (T0 runtime).
// Flat 8-step recurrence, NO dead-step guard (r13: runtime guard broke the
// compiler schedule, MfmaUtil 34->30, +22 us).
// launch_bounds(256,3): cap ~170, demand ~110 -> NO SPILL; measured 225 us (r12).
// (256,4)=237 (r9/r10); (256,5)/(256,6) spill catastrophically (r8/r11).
template<int NTC, int KRT>
__global__ __launch_bounds__(256, 3)
void gemm_mix_rec4_kernel(const unsigned short* __restrict__ hp,   // hpack [V][256][8]
                          const unsigned short* __restrict__ Bp,   // packed [w_mix ; w_res]
                          const unsigned short* __restrict__ Ares, // residual rows [T][V][KR]
                          const float* __restrict__ lam,           // [4096]
                          const float* __restrict__ Bv,            // [4096]
                          const float* __restrict__ bias,          // [256] = b_mix + b_res
                          unsigned short* __restrict__ out,        // rows at (t-OB)*V
                          int T0base, int OB) {
    constexpr int KR = KRT * 32;
    __shared__ __align__(16) unsigned short Afrag[2][4 * NTC * 64 * 8];
    const int tid = threadIdx.x;
    const int w = tid >> 6, lane = tid & 63;
    const int quad = lane >> 4, l16 = lane & 15;
    const int T0 = T0base + blockIdx.x * NTC;
    const int m0 = blockIdx.y * 16;
    // phase-1 assignment: 16 rows x 16 octets (8 k each) = 128 k per phase
    const int prow = tid & 15;
    const int oct  = tid >> 4;           // 0..15
    const int kt_w = oct >> 2, qo = oct & 3;
    const int vr = m0 + prow;

    floatx4 acc[NTC][4];
#pragma unroll
    for (int t = 0; t < NTC; ++t)
#pragma unroll
        for (int i = 0; i < 4; ++i) acc[t][i] = (floatx4){0.f,0.f,0.f,0.f};

    const unsigned short* bptr = Bp + ((size_t)(w * 4) * 64 + lane) * 8;

    auto compute = [&](int ph, int buf) {
        const int kg = ph * 128 + kt_w * 32 + qo * 8;
        const int ch = kg >> 4;
        PK h8; h8.u = *(const uint4*)(hp + (size_t)vr * 2048 + (size_t)ch * 8);
        floatx4 l0 = *(const floatx4*)(lam + kg);
        floatx4 l1 = *(const floatx4*)(lam + kg + 4);
        floatx4 b0 = *(const floatx4*)(Bv + kg);
        floatx4 b1 = *(const floatx4*)(Bv + kg + 4);
        floatx4 sA = {0.f,0.f,0.f,0.f}, sB = {0.f,0.f,0.f,0.f};
        unsigned short* ap = Afrag[buf] + ((size_t)(kt_w * NTC) * 64 + qo * 16 + prow) * 8;
#pragma unroll
        for (int t = 0; t < 8; ++t) {
            float hv = bf2f((unsigned int)(unsigned short)h8.s[t]);
            floatx4 hvv = {hv, hv, hv, hv};
            sA = l0 * sA + hvv * b0;     // v_pk_fma_f32
            sB = l1 * sB + hvv * b1;
            if ((unsigned)(t - T0) < (unsigned)NTC) {
                PK cv;
                cv.u.x = cvtpk_bf16(sA[0], sA[1]);
                cv.u.y = cvtpk_bf16(sA[2], sA[3]);
                cv.u.z = cvtpk_bf16(sB[0], sB[1]);
                cv.u.w = cvtpk_bf16(sB[2], sB[3]);
                PK st; st.s = relu8(cv.s);
                *(uint4*)(ap + (size_t)(t - T0) * 512) = st.u;   // ds_write_b128
            }
        }
    };
    auto consume = [&](int buf) {
#pragma unroll
        for (int kt = 0; kt < 4; ++kt) {
            short8 bfr[4];
#pragma unroll
            for (int i = 0; i < 4; ++i) bfr[i] = *(const short8*)(bptr + i * 512);
            __builtin_amdgcn_s_setprio(1);
#pragma unroll
            for (int ts = 0; ts < NTC; ++ts) {
                short8 af = *(const short8*)(Afrag[buf] + (size_t)((kt * NTC + ts) * 64 + lane) * 8);
#pragma unroll
                for (int i = 0; i < 4; ++i)
                    acc[ts][i] = __builtin_amdgcn_mfma_f32_16x16x32_bf16(af, bfr[i], acc[ts][i], 0, 0, 0);
            }
            __builtin_amdgcn_s_setprio(0);
            bptr += 16 * 512;
        }
    };

    compute(0, 0);
    __syncthreads();
    for (int ph = 0; ph < 32; ++ph) {
        if (ph < 31) compute(ph + 1, (ph + 1) & 1);
        consume(ph & 1);
        __syncthreads();
    }

    // ---- residual tail: acc[ts] += x(T0+ts) @ w_res ----
#pragma unroll
    for (int ktr = 0; ktr < KRT; ++ktr) {
        short8 bfr[4];
#pragma unroll
        for (int i = 0; i < 4; ++i) bfr[i] = *(const short8*)(bptr + i * 512);
#pragma unroll
        for (int ts = 0; ts < NTC; ++ts) {
            const unsigned short* ar = Ares + ((size_t)(T0 + ts) * V_DIM + (size_t)(m0 + l16)) * KR + ktr * 32 + quad * 8;
            short8 af = *(const short8*)ar;
#pragma unroll
            for (int i = 0; i < 4; ++i)
                acc[ts][i] = __builtin_amdgcn_mfma_f32_16x16x32_bf16(af, bfr[i], acc[ts][i], 0, 0, 0);
        }
        bptr += 16 * 512;
    }
    // ---- epilogue: bias + bf16 store, per chunk t ----
#pragma unroll
    for (int ts = 0; ts < NTC; ++ts) {
#pragma unroll
        for (int i = 0; i < 4; ++i) {
            int col = w * 64 + i * 16 + l16;
            float b = bias[col];
#pragma unroll
            for (int rr = 0; rr < 4; ++rr) {
                int row = m0 + quad * 4 + rr;
                out[((size_t)(T0 + ts - OB) * V_DIM + row) * 256 + col] = (unsigned short)f2bf(acc[ts][i][rr] + b);
            }
        }
    }
}

// ---- small GEMM (head): 32-row blocks, 8 waves ----
template<int NT, int NTN_TOT, bool RELU>
__global__ __launch_bounds__(512)
void gemm16_kernel(const unsigned short* __restrict__ A, const unsigned short* __restrict__ Bp,
                   const float* __restrict__ bias, float* __restrict__ outF, int M, int K) {
    const int w = threadIdx.x >> 6, lane = threadIdx.x & 63;
    const int quad = lane >> 4, l16 = lane & 15;
    const int rowgrp = w >> 2, nchunk = w & 3;
    const int m0 = blockIdx.x * 32 + rowgrp * 16;
    const int ntb = nchunk * NT;
    constexpr int Ntot = NTN_TOT * 16;
    floatx4 acc[NT];
#pragma unroll
    for (int i = 0; i < NT; ++i) acc[i] = (floatx4){0.f,0.f,0.f,0.f};
    int r = m0 + l16; if (r > M - 1) r = M - 1;
    const unsigned short* arow = A + (size_t)r * K + quad * 8;
    const int ksteps = K >> 5;
    for (int kt = 0; kt < ksteps; ++kt) {
        short8 af = *(const short8*)(arow + kt * 32);
        if (RELU) af = relu8(af);
#pragma unroll
        for (int i = 0; i < NT; ++i) {
            short8 bf = *(const short8*)(Bp + ((size_t)(kt * NTN_TOT + ntb + i) * 64 + lane) * 8);
            acc[i] = __builtin_amdgcn_mfma_f32_16x16x32_bf16(af, bf, acc[i], 0, 0, 0);
        }
    }
    const int rbase = m0 + quad * 4;
#pragma unroll
    for (int i = 0; i < NT; ++i) {
        int col = (ntb + i) * 16 + l16;
        float b = bias[col];
#pragma unroll
        for (int rr = 0; rr < 4; ++rr) {
            int row = rbase + rr;
            if (row < M)
                outF[(size_t)row * Ntot + col] = acc[i][rr] + b;
        }
    }
}

extern "C" void kernel_launch(void* const* d_in, const int* in_sizes, int n_in,
                              void* d_out, int out_size, void* d_ws, size_t ws_size,
                              hipStream_t stream) {
    const float* xs      = (const float*)d_in[0];
    const int*   ei      = (const int*)d_in[1];
    const float* w_pre   = (const float*)d_in[2];
    const float* b_pre   = (const float*)d_in[3];
    const float* w_res0  = (const float*)d_in[4];
    const float* b_res0  = (const float*)d_in[5];
    const float* w_self0 = (const float*)d_in[6];
    const float* w_neigh0= (const float*)d_in[7];
    const float* b_sage0 = (const float*)d_in[8];
    const float* a_log0  = (const float*)d_in[9];
    const float* B0      = (const float*)d_in[10];
    const float* w_mix0  = (const float*)d_in[11];
    const float* b_mix0  = (const float*)d_in[12];
    const float* w_res1  = (const float*)d_in[13];
    const float* b_res1  = (const float*)d_in[14];
    const float* w_self1 = (const float*)d_in[15];
    const float* w_neigh1= (const float*)d_in[16];
    const float* b_sage1 = (const float*)d_in[17];
    const float* a_log1  = (const float*)d_in[18];
    const float* B1      = (const float*)d_in[19];
    const float* w_mix1  = (const float*)d_in[20];
    const float* b_mix1  = (const float*)d_in[21];
    const float* w_out   = (const float*)d_in[22];
    const float* b_out   = (const float*)d_in[23];

    char* wsB = (char*)d_ws;
    size_t off = 0;
    auto alloc = [&](size_t bytes) {
        char* p = wsB + off;
        off += (bytes + 255) & ~(size_t)255;
        return p;
    };
    unsigned short* x0b   = (unsigned short*)alloc((size_t)M_ALL * 128 * 2);   // token-mixed input, all t
    unsigned short* xm    = (unsigned short*)alloc((size_t)M_ALL * 256 * 2);   // aggregated-x (both layers)
    unsigned short* hpack = (unsigned short*)alloc((size_t)V_DIM * 2048 * 2);  // [V][256][8] (both layers)
    unsigned short* x1b   = (unsigned short*)alloc((size_t)M_ALL * 256 * 2);   // layer-0 output, all t
    unsigned short* out1_b= (unsigned short*)alloc((size_t)V_DIM * 256 * 2);
    int*            deg_cnt = (int*)alloc((size_t)T_DIM * V_DIM * 4);
    float*          invdeg  = (float*)alloc((size_t)T_DIM * V_DIM * 4);
    int*            rowptr  = (int*)alloc((size_t)T_DIM * (V_DIM + 1) * 4);
    int*            fill_cnt= (int*)alloc((size_t)T_DIM * V_DIM * 4);
    int*            srcs    = (int*)alloc((size_t)T_DIM * E_DIM * 4);
    float*          lam0  = (float*)alloc(4096 * 4);
    float*          lam1  = (float*)alloc(4096 * 4);
    float*          bmt0  = (float*)alloc(256 * 4);
    float*          bmt1  = (float*)alloc(256 * 4);
    unsigned short* wcat0p= (unsigned short*)alloc((size_t)256 * 256 * 2);   // [self;neigh] K'=256
    unsigned short* wcat1p= (unsigned short*)alloc((size_t)512 * 256 * 2);   // [self;neigh] K'=512
    unsigned short* wmix0p= (unsigned short*)alloc((size_t)(4096 + 128) * 256 * 2);
    unsigned short* wmix1p= (unsigned short*)alloc((size_t)(4096 + 256) * 256 * 2);
    unsigned short* woutp = (unsigned short*)alloc((size_t)256 * 64 * 2);
    if (off > ws_size) return;   // fail cleanly, not a GPU fault

    auto cdiv = [](int a, int b) { return (a + b - 1) / b; };
    const int gMall = M_ALL / 64;               // 1250 (exact)
    const int gGat  = M_ALL / 4;                // 20000 blocks, 4 rows each (div by 8)

    // ---- parameter prep ----
    lamb_kernel<<<16, 256, 0, stream>>>(a_log0, a_log1, b_mix0, b_res0, b_mix1, b_res1,
                                        lam0, lam1, bmt0, bmt1);
    // fused SAGE weights: [w_self ; w_neigh] along K, NTN_tot = 16
    pack_b_kernel<<<cdiv(4*16*64, 256), 256, 0, stream>>>(w_self0,  wcat0p, 128, 256, 16, 0, 0);
    pack_b_kernel<<<cdiv(4*16*64, 256), 256, 0, stream>>>(w_neigh0, wcat0p, 128, 256, 16, 0, 4);
    pack_b_kernel<<<cdiv(8*16*64, 256), 256, 0, stream>>>(w_self1,  wcat1p, 256, 256, 16, 0, 0);
    pack_b_kernel<<<cdiv(8*16*64, 256), 256, 0, stream>>>(w_neigh1, wcat1p, 256, 256, 16, 0, 8);
    // mix weights with residual appended along K (kt_off = 128)
    pack_b_kernel<<<cdiv(128*16*64, 256), 256, 0, stream>>>(w_mix0, wmix0p, 4096, 256, 16, 0, 0);
    pack_b_kernel<<<cdiv(4*16*64, 256),   256, 0, stream>>>(w_res0, wmix0p, 128,  256, 16, 0, 128);
    pack_b_kernel<<<cdiv(128*16*64, 256), 256, 0, stream>>>(w_mix1, wmix1p, 4096, 256, 16, 0, 0);
    pack_b_kernel<<<cdiv(8*16*64, 256),   256, 0, stream>>>(w_res1, wmix1p, 256,  256, 16, 0, 128);
    pack_b_kernel<<<cdiv(8*4*64, 256), 256, 0, stream>>>(w_out, woutp, 256, 64, 4, 0, 0);

    // ---- token mixer + CSR build ----
    token_mix_kernel<<<cdiv(T_DIM*V_DIM*128/4, 256), 256, 0, stream>>>(xs, w_pre, b_pre, x0b);
    hipMemsetAsync(deg_cnt, 0, (size_t)T_DIM * V_DIM * 4, stream);
    hipMemsetAsync(fill_cnt, 0, (size_t)T_DIM * V_DIM * 4, stream);
    deg_kernel<<<cdiv(T_DIM*E_DIM, 256), 256, 0, stream>>>(ei, deg_cnt);
    scan_kernel<<<T_DIM, 1024, 0, stream>>>(deg_cnt, rowptr);
    invdeg_kernel<<<cdiv(T_DIM*V_DIM, 256), 256, 0, stream>>>(deg_cnt, invdeg);
    fill_kernel<<<cdiv(T_DIM*E_DIM, 256), 256, 0, stream>>>(ei, rowptr, fill_cnt, srcs);

    // ================= layer 0 (batched over all t) =================
    gather_x_kernel<128><<<gGat, 256, 0, stream>>>(x0b, srcs, rowptr, invdeg, xm);
    gemm_catf_kernel<4><<<gMall, 256, 0, stream>>>(x0b, xm, wcat0p, b_sage0, hpack, M_ALL);
    gemm_mix_rec4_kernel<4, 4><<<dim3(2, V_DIM / 16), 256, 0, stream>>>(
        hpack, wmix0p, x0b, lam0, B0, bmt0, x1b, 0, 0);

    // ================= layer 1 (batched over all t; mix only at t=7) =================
    gather_x_kernel<256><<<gGat, 256, 0, stream>>>(x1b, srcs, rowptr, invdeg, xm);
    gemm_catf_kernel<8><<<gMall, 256, 0, stream>>>(x1b, xm, wcat1p, b_sage1, hpack, M_ALL);
    gemm_mix_rec4_kernel<1, 8><<<dim3(1, V_DIM / 16), 256, 0, stream>>>(
        hpack, wmix1p, x1b, lam1, B1, bmt1, out1_b, 7, 7);

    // ================= head =================
    gemm16_kernel<1, 4, false><<<cdiv(V_DIM,32), 512, 0, stream>>>(
        out1_b, woutp, b_out, (float*)d_out, V_DIM, 256);
}